// Round 1
// 895.643 us; speedup vs baseline: 1.0348x; 1.0348x over previous
//
#include <hip/hip_runtime.h>
#include <math.h>

#define KK 4
#define BB 2
#define SS 1024
#define DD 1024
#define EPSV 1e-6f
#define BSD   (BB*SS*DD)        // 2097152
#define NBSD  (KK*BB*SS*DD)     // 8388608
#define ROWS  (KK*BB*SS)        // 8192
#define NSLOTS 64
#define NACC 24                 // 16 res + 4 pre + 4 post
#define ACC_N (NSLOTS*NACC)     // 1536

typedef float v4f __attribute__((ext_vector_type(4)));

// ---------------- Kernel 1: rmsnorm stats + the 24 global dot-products ----------------
// v2: (a) first alpha tiles issued BEFORE the norm reduce (independent of inv) so
// their HBM latency hides under the shuffle-reduce + barriers; (b) all 20 xn values a
// thread needs are pulled into registers once, so the streaming loop is pure
// global_load+FMA with no per-iteration ds_read/lgkmcnt on the critical path;
// (c) nontemporal loads for the 839 MB of stream-once alpha data (zero reuse).
__global__ __launch_bounds__(256) void k1_reduce(const float* __restrict__ x,
                                                 const float* __restrict__ w,
                                                 const float* __restrict__ res_a,
                                                 const float* __restrict__ pre_a,
                                                 const float* __restrict__ post_a,
                                                 float* __restrict__ ws_acc,
                                                 float* __restrict__ ws_inv) {
    const int row  = blockIdx.x;        // n*B*S + b*S + s
    const int t    = threadIdx.x;       // 0..255
    const int wave = t >> 6, lane = t & 63;

    __shared__ float s_xn[DD];          // 4 KB normalized row
    __shared__ float s_ss[4];

    const v4f* ra = (const v4f*)(res_a  + (size_t)row * (DD*16));
    const v4f* pa = (const v4f*)(pre_a  + (size_t)row * (DD*4));
    const v4f* qa = (const v4f*)(post_a + (size_t)row * (DD*4));

    v4f xv = ((const v4f*)(x + (size_t)row * DD))[t];
    v4f wv = ((const v4f*)w)[t];

    // Early-issue the first alpha tiles (do NOT depend on inv).
    v4f r0 = __builtin_nontemporal_load(ra + t);           // res c=0
    v4f r1 = __builtin_nontemporal_load(ra + 256 + t);     // res c=1
    v4f p0 = __builtin_nontemporal_load(pa + t);           // pre c=0
    v4f q0 = __builtin_nontemporal_load(qa + t);           // post c=0

    float ss = xv.x*xv.x + xv.y*xv.y + xv.z*xv.z + xv.w*xv.w;
    #pragma unroll
    for (int o = 32; o > 0; o >>= 1) ss += __shfl_down(ss, o, 64);
    if (lane == 0) s_ss[wave] = ss;
    __syncthreads();
    const float inv = rsqrtf((s_ss[0] + s_ss[1] + s_ss[2] + s_ss[3]) * (1.0f / (float)DD) + EPSV);
    if (t == 0) ws_inv[row] = inv;

    v4f xn = xv * wv;
    xn *= inv;
    ((v4f*)s_xn)[t] = xn;
    __syncthreads();

    // Pull every xn value this thread will ever need into registers (20 floats),
    // so the streaming loop has zero LDS reads.
    float xr[16];                       // res: xs = s_xn[c*64 + (t>>2)]
    #pragma unroll
    for (int c = 0; c < 16; c++) xr[c] = s_xn[c*64 + (t >> 2)];
    float xpq[4];                       // pre/post: xs = s_xn[c*256 + t]
    #pragma unroll
    for (int c = 0; c < 4; c++) xpq[c] = s_xn[c*256 + t];

    // --- res_alpha: 16384 floats/row = 4096 float4. float4 g covers d=g>>2,
    // m16 = 4*(g&3)+{0..3}. Thread t's class (t&3) is fixed -> 4 accumulators.
    float ar[4], ap[4], aq[4];
    ar[0] = xr[0]*r0.x + xr[1]*r1.x;
    ar[1] = xr[0]*r0.y + xr[1]*r1.y;
    ar[2] = xr[0]*r0.z + xr[1]*r1.z;
    ar[3] = xr[0]*r0.w + xr[1]*r1.w;
    ap[0] = xpq[0]*p0.x; ap[1] = xpq[0]*p0.y; ap[2] = xpq[0]*p0.z; ap[3] = xpq[0]*p0.w;
    aq[0] = xpq[0]*q0.x; aq[1] = xpq[0]*q0.y; aq[2] = xpq[0]*q0.z; aq[3] = xpq[0]*q0.w;

    // Streaming loop: res c=2..15, pre/post c=1..3 folded in to mix the streams.
    #pragma unroll
    for (int c = 2; c < 16; c++) {
        v4f a = __builtin_nontemporal_load(ra + c*256 + t);
        const float xs = xr[c];
        ar[0] += xs*a.x; ar[1] += xs*a.y;
        ar[2] += xs*a.z; ar[3] += xs*a.w;
        if (c <= 4) {                   // static under full unroll
            v4f p = __builtin_nontemporal_load(pa + (c-1)*256 + t);
            v4f q = __builtin_nontemporal_load(qa + (c-1)*256 + t);
            const float xs2 = xpq[c-1];
            ap[0] += xs2*p.x; ap[1] += xs2*p.y; ap[2] += xs2*p.z; ap[3] += xs2*p.w;
            aq[0] += xs2*q.x; aq[1] += xs2*q.y; aq[2] += xs2*q.z; aq[3] += xs2*q.w;
        }
    }

    // --- reduce: res over residue-4 lane classes; pre/post over full wave.
    #pragma unroll
    for (int j = 0; j < 4; j++) {
        #pragma unroll
        for (int o = 32; o >= 4; o >>= 1) ar[j] += __shfl_down(ar[j], o, 64);
        #pragma unroll
        for (int o = 32; o >= 1; o >>= 1) {
            ap[j] += __shfl_down(ap[j], o, 64);
            aq[j] += __shfl_down(aq[j], o, 64);
        }
    }
    __shared__ float s_red[4][NACC];
    if (lane < 4) {             // lane i holds res m16 = 4*i + {0..3}
        #pragma unroll
        for (int j = 0; j < 4; j++) s_red[wave][lane*4 + j] = ar[j];
    }
    if (lane == 0) {
        #pragma unroll
        for (int j = 0; j < 4; j++) { s_red[wave][16 + j] = ap[j]; s_red[wave][20 + j] = aq[j]; }
    }
    __syncthreads();
    if (t < NACC) {
        float v = s_red[0][t] + s_red[1][t] + s_red[2][t] + s_red[3][t];
        atomicAdd(&ws_acc[(row & (NSLOTS-1)) * NACC + t], v);
    }
}

// ---------------- Kernel 2: fold slots, sigmoids, 4x4 log-Sinkhorn ----------------
// v2: slot fold parallelized over 24 threads (1536 L2-resident loads in flight
// instead of a single serial thread); sinkhorn tail stays scalar (tiny).
__global__ void k2_maps(const float* __restrict__ ws_acc,
                        const float* __restrict__ res_beta,
                        const float* __restrict__ pre_beta,
                        const float* __restrict__ post_beta,
                        float* __restrict__ maps) {
    __shared__ float s_h[NACC];
    const int t = threadIdx.x;
    if (t < NACC) {
        float s = 0.f;
        #pragma unroll
        for (int sl = 0; sl < NSLOTS; sl++) s += ws_acc[sl*NACC + t];
        s_h[t] = s;
    }
    __syncthreads();
    if (t != 0) return;

    float h[NACC];
    #pragma unroll
    for (int j = 0; j < NACC; j++) h[j] = s_h[j];

    for (int i = 0; i < 4; i++) {
        float hp = 1e-4f * h[16+i] + pre_beta[i];
        maps[i]     = 1.f / (1.f + expf(-hp));          // pre_mapping (scale 1.0)
        float hq = 1e-4f * h[20+i] + post_beta[i];
        maps[4+i]   = 2.f / (1.f + expf(-hq));          // post_mapping (scale 2.0)
    }
    float Z[4][4];
    for (int i = 0; i < 4; i++)
        for (int j = 0; j < 4; j++)
            Z[i][j] = (1e-4f * h[i*4 + j] + res_beta[j]) * (1.0f / 0.05f);
    float u[4] = {0,0,0,0}, v[4] = {0,0,0,0};
    for (int it = 0; it < 20; it++) {
        for (int i = 0; i < 4; i++) {
            float m = Z[i][0]+v[0];
            for (int j = 1; j < 4; j++) { float tt = Z[i][j]+v[j]; m = tt > m ? tt : m; }
            float s = 0.f;
            for (int j = 0; j < 4; j++) s += expf(Z[i][j]+v[j]-m);
            u[i] = -(m + logf(s));
        }
        for (int j = 0; j < 4; j++) {
            float m = Z[0][j]+u[0];
            for (int i = 1; i < 4; i++) { float tt = Z[i][j]+u[i]; m = tt > m ? tt : m; }
            float s = 0.f;
            for (int i = 0; i < 4; i++) s += expf(Z[i][j]+u[i]-m);
            v[j] = -(m + logf(s));
        }
    }
    for (int i = 0; i < 4; i++)
        for (int j = 0; j < 4; j++)
            maps[8 + i*4 + j] = expf(Z[i][j] + u[i] + v[j]);   // res_map[n][m]
}

// ---------------- Kernel 3: outputs ----------------
// v2: bs is block-uniform (one (b,s) row per block) so the 4 ws_inv loads
// scalarize; outputs (never re-read) use nontemporal stores; x re-read (already
// evicted from L3 by k1's 839 MB stream) uses nontemporal loads.
__global__ __launch_bounds__(256) void k3_out(const float* __restrict__ x,
                                              const float* __restrict__ w,
                                              const float* __restrict__ ws_inv,
                                              const float* __restrict__ maps,
                                              float* __restrict__ out) {
    const int bs   = blockIdx.x;                       // b*S + s
    const size_t e = (size_t)bs * DD + (threadIdx.x << 2);

    float pre_m[4], post_m[4], rm[16], iv[4];
    #pragma unroll
    for (int i = 0; i < 4; i++) {
        pre_m[i]  = maps[i];
        post_m[i] = maps[4+i];
        iv[i]     = ws_inv[i * (BB*SS) + bs];
    }
    #pragma unroll
    for (int i = 0; i < 16; i++) rm[i] = maps[8+i];

    v4f wv = *(const v4f*)(w + (threadIdx.x << 2));

    float li_x = 0.f, li_y = 0.f, li_z = 0.f, li_w = 0.f;
    v4f res[4];
    #pragma unroll
    for (int m = 0; m < 4; m++) res[m] = (v4f){0.f, 0.f, 0.f, 0.f};

    #pragma unroll
    for (int n = 0; n < 4; n++) {
        v4f xv = __builtin_nontemporal_load((const v4f*)(x + (size_t)n * BSD + e));
        const float invn = iv[n];
        float xnx = xv.x * invn * wv.x;
        float xny = xv.y * invn * wv.y;
        float xnz = xv.z * invn * wv.z;
        float xnw = xv.w * invn * wv.w;
        const float pm = pre_m[n];
        li_x += xnx * pm; li_y += xny * pm; li_z += xnz * pm; li_w += xnw * pm;
        #pragma unroll
        for (int m = 0; m < 4; m++) {
            const float r = rm[n*4 + m];
            res[m].x += xnx * r; res[m].y += xny * r;
            res[m].z += xnz * r; res[m].w += xnw * r;
        }
    }
    #pragma unroll
    for (int m = 0; m < 4; m++)
        __builtin_nontemporal_store(res[m], (v4f*)(out + (size_t)m * BSD + e));
    #pragma unroll
    for (int n = 0; n < 4; n++) {
        v4f o = (v4f){li_x * post_m[n], li_y * post_m[n], li_z * post_m[n], li_w * post_m[n]};
        __builtin_nontemporal_store(o, (v4f*)(out + (size_t)NBSD + (size_t)n * BSD + e));
    }
}

extern "C" void kernel_launch(void* const* d_in, const int* in_sizes, int n_in,
                              void* d_out, int out_size, void* d_ws, size_t ws_size,
                              hipStream_t stream) {
    const float* x      = (const float*)d_in[0];
    const float* w      = (const float*)d_in[1];
    const float* res_a  = (const float*)d_in[2];
    const float* pre_a  = (const float*)d_in[3];
    const float* post_a = (const float*)d_in[4];
    const float* res_b  = (const float*)d_in[5];
    const float* pre_b  = (const float*)d_in[6];
    const float* post_b = (const float*)d_in[7];

    float* ws      = (float*)d_ws;
    float* ws_acc  = ws;                      // NSLOTS*NACC floats
    float* ws_inv  = ws + ACC_N;              // ROWS floats
    float* ws_maps = ws + ACC_N + ROWS;       // 24 floats

    hipMemsetAsync(ws_acc, 0, NSLOTS * NACC * sizeof(float), stream);

    k1_reduce<<<ROWS, 256, 0, stream>>>(x, w, res_a, pre_a, post_a, ws_acc, ws_inv);
    k2_maps<<<1, 64, 0, stream>>>(ws_acc, res_b, pre_b, post_b, ws_maps);
    k3_out<<<BSD/1024, 256, 0, stream>>>(x, w, ws_inv, ws_maps, (float*)d_out);
}